// Round 1
// baseline (801.265 us; speedup 1.0000x reference)
//
#include <hip/hip_runtime.h>
#include <hip/hip_bf16.h>

typedef short bf16x8 __attribute__((ext_vector_type(8)));
typedef float f32x4 __attribute__((ext_vector_type(4)));
using bf16 = __hip_bfloat16;

#define Bb 8
#define Kk 2048
#define Dd 512
#define Ee 1024
#define Ss 128
#define Mrows (Bb*Kk)
#define Ff (2*Ee+Ss)

#define BM 128
#define BN 128
#define BK 64
#define LDK 72   // 64 + 8 pad (keeps 16B alignment, breaks pow2 bank stride)

static __device__ __forceinline__ float bf2f(bf16 v){ return __bfloat162float(v); }
static __device__ __forceinline__ bf16 f2bf(float v){ return __float2bfloat16(v); }

// ---------------- cast f32 -> bf16 ----------------
__global__ void cast_k(const float* __restrict__ in, bf16* __restrict__ out, int n) {
    int i = blockIdx.x * blockDim.x + threadIdx.x;
    if (i < n) out[i] = f2bf(in[i]);
}

// ---------------- RMS-norm-like: xn = x / max(||x||/sqrt(D), eps) * g ----------------
__global__ __launch_bounds__(256) void rmsnorm_k(const float* __restrict__ x,
                                                 const float* __restrict__ g,
                                                 bf16* __restrict__ xn) {
    int row = blockIdx.x;
    int t = threadIdx.x;
    const float2* xr = (const float2*)(x + (size_t)row * Dd);
    float2 v = xr[t];                        // 256 threads * 2 = 512
    float ss = v.x * v.x + v.y * v.y;
    #pragma unroll
    for (int off = 32; off; off >>= 1) ss += __shfl_down(ss, off);
    __shared__ float red[4];
    if ((t & 63) == 0) red[t >> 6] = ss;
    __syncthreads();
    float tot = red[0] + red[1] + red[2] + red[3];
    float norm = sqrtf(tot * (1.0f / Dd));
    float scale = g[0] / fmaxf(norm, 1e-5f);
    bf16* o = xn + (size_t)row * Dd;
    o[2 * t]     = f2bf(v.x * scale);
    o[2 * t + 1] = f2bf(v.y * scale);
}

// ---------------- 64x64 tile transpose: v[2048][1024] -> vT[1024][2048] per batch ----------------
__global__ __launch_bounds__(256) void transpose_k(const bf16* __restrict__ in, bf16* __restrict__ out) {
    __shared__ bf16 tile[64][66];            // pad 2 -> conflict-free column reads
    int e0 = blockIdx.x * 64, j0 = blockIdx.y * 64, b = blockIdx.z;
    const bf16* ib = in  + (size_t)b * Kk * Ee;
    bf16*       ob = out + (size_t)b * Ee * Kk;
    int t = threadIdx.x;
    #pragma unroll
    for (int it = 0; it < 16; ++it) {
        int idx = t + it * 256;
        int j = idx >> 6, e = idx & 63;
        tile[j][e] = ib[(size_t)(j0 + j) * Ee + e0 + e];
    }
    __syncthreads();
    #pragma unroll
    for (int it = 0; it < 16; ++it) {
        int idx = t + it * 256;
        int e = idx >> 6, j = idx & 63;
        ob[(size_t)(e0 + e) * Kk + j0 + j] = tile[j][e];
    }
}

// ---------------- generic NT GEMM: C[m][n] = sum_k A[m][k] * B[n][k] ----------------
// EPI 0: silu + split into u / v(tmp) / q,k (gamma,beta)   [GEMM1]
// EPI 1: P = relu(acc/sqrt(S))^2                           [GEMM2]
// EPI 2: agg = acc * u                                     [GEMM3]
// EPI 3: out = x*res_scale + acc (f32)                     [GEMM4]
template<int EPI>
__global__ __launch_bounds__(256, 2)
void gemm_nt(const bf16* __restrict__ A, int lda, long long sA,
             const bf16* __restrict__ B, int ldb, long long sB, int nk,
             void* __restrict__ o0, void* __restrict__ o1,
             void* __restrict__ o2, void* __restrict__ o3,
             const float* __restrict__ gamma, const float* __restrict__ beta) {
    __shared__ bf16 As[BM][LDK];
    __shared__ bf16 Bs[BN][LDK];

    const int t  = threadIdx.x;
    const int bz = blockIdx.z;
    const int tM = blockIdx.y, tN = blockIdx.x;
    const bf16* Ab = A + (size_t)bz * sA + (size_t)tM * BM * lda;
    const bf16* Bp = B + (size_t)bz * sB + (size_t)tN * BN * ldb;

    int r_[4], kc_[4];
    #pragma unroll
    for (int it = 0; it < 4; ++it) { int c = t + it * 256; r_[it] = c >> 3; kc_[it] = (c & 7) * 8; }

    int4 ra[4], rb[4];
    #pragma unroll
    for (int it = 0; it < 4; ++it) {
        ra[it] = *(const int4*)(Ab + (size_t)r_[it] * lda + kc_[it]);
        rb[it] = *(const int4*)(Bp + (size_t)r_[it] * ldb + kc_[it]);
    }

    const int lane = t & 63;
    const int wave = t >> 6;
    const int wr = (wave >> 1) * 64, wc = (wave & 1) * 64;
    const int fr = lane & 15;
    const int ko = (lane >> 4) * 8;
    const int q4 = (lane >> 4) * 4;

    f32x4 acc[4][4] = {};

    for (int kt = 0; kt < nk; ++kt) {
        __syncthreads();
        #pragma unroll
        for (int it = 0; it < 4; ++it) {
            *(int4*)&As[r_[it]][kc_[it]] = ra[it];
            *(int4*)&Bs[r_[it]][kc_[it]] = rb[it];
        }
        __syncthreads();
        if (kt + 1 < nk) {
            int koff = (kt + 1) * BK;
            #pragma unroll
            for (int it = 0; it < 4; ++it) {
                ra[it] = *(const int4*)(Ab + (size_t)r_[it] * lda + koff + kc_[it]);
                rb[it] = *(const int4*)(Bp + (size_t)r_[it] * ldb + koff + kc_[it]);
            }
        }
        #pragma unroll
        for (int kk = 0; kk < 2; ++kk) {
            bf16x8 af[4], bv[4];
            #pragma unroll
            for (int m = 0; m < 4; ++m) af[m] = *(const bf16x8*)&As[wr + m * 16 + fr][kk * 32 + ko];
            #pragma unroll
            for (int n = 0; n < 4; ++n) bv[n] = *(const bf16x8*)&Bs[wc + n * 16 + fr][kk * 32 + ko];
            #pragma unroll
            for (int m = 0; m < 4; ++m)
                #pragma unroll
                for (int n = 0; n < 4; ++n)
                    acc[m][n] = __builtin_amdgcn_mfma_f32_16x16x32_bf16(af[m], bv[n], acc[m][n], 0, 0, 0);
        }
    }

    const int row0 = tM * BM + wr + q4;   // + m*16 + j
    const int col0 = tN * BN + wc + fr;   // + n*16

    #pragma unroll
    for (int m = 0; m < 4; ++m) {
        #pragma unroll
        for (int n = 0; n < 4; ++n) {
            #pragma unroll
            for (int j = 0; j < 4; ++j) {
                float val = acc[m][n][j];
                int rrow = row0 + m * 16 + j;
                int ccol = col0 + n * 16;
                if (EPI == 0) {
                    float s = val / (1.0f + __expf(-val));   // silu
                    if (ccol < Ee) {
                        ((bf16*)o0)[(size_t)rrow * Ee + ccol] = f2bf(s);
                    } else if (ccol < 2 * Ee) {
                        ((bf16*)o1)[(size_t)rrow * Ee + (ccol - Ee)] = f2bf(s);  // v (untransposed tmp)
                    } else {
                        int si = ccol - 2 * Ee;
                        ((bf16*)o2)[(size_t)rrow * Ss + si] = f2bf(s * gamma[si]      + beta[si]);
                        ((bf16*)o3)[(size_t)rrow * Ss + si] = f2bf(s * gamma[Ss + si] + beta[Ss + si]);
                    }
                } else if (EPI == 1) {
                    float sc = val * 0.08838834764831845f;   // 1/sqrt(128)
                    float r = fmaxf(sc, 0.0f);
                    ((bf16*)o0)[(size_t)bz * Kk * Kk + (size_t)rrow * Kk + ccol] = f2bf(r * r);
                } else if (EPI == 2) {
                    size_t idx = ((size_t)bz * Kk + rrow) * Ee + ccol;
                    float uu = bf2f(((const bf16*)o1)[idx]);
                    ((bf16*)o0)[idx] = f2bf(val * uu);
                } else {
                    size_t idx = (size_t)rrow * Dd + ccol;
                    ((float*)o0)[idx] = ((const float*)o1)[idx] * ((const float*)o2)[ccol] + val;
                }
            }
        }
    }
}

extern "C" void kernel_launch(void* const* d_in, const int* in_sizes, int n_in,
                              void* d_out, int out_size, void* d_ws, size_t ws_size,
                              hipStream_t stream) {
    const float* x         = (const float*)d_in[0];
    const float* uv_w      = (const float*)d_in[1];
    const float* o_w       = (const float*)d_in[2];
    const float* gamma     = (const float*)d_in[3];
    const float* beta      = (const float*)d_in[4];
    const float* g         = (const float*)d_in[5];
    const float* res_scale = (const float*)d_in[6];
    float* out = (float*)d_out;

    char* ws = (char*)d_ws;
    size_t off = 0;
    auto alloc = [&](size_t bytes) { void* p = ws + off; off += (bytes + 255) & ~(size_t)255; return p; };

    bf16* xn   = (bf16*)alloc((size_t)Mrows * Dd * 2);
    bf16* uvwb = (bf16*)alloc((size_t)Ff * Dd * 2);
    bf16* owb  = (bf16*)alloc((size_t)Dd * Ee * 2);
    bf16* u    = (bf16*)alloc((size_t)Mrows * Ee * 2);
    bf16* qb   = (bf16*)alloc((size_t)Mrows * Ss * 2);
    bf16* kb   = (bf16*)alloc((size_t)Mrows * Ss * 2);
    bf16* P    = (bf16*)alloc((size_t)Bb * Kk * Kk * 2);
    bf16* agg  = (bf16*)alloc((size_t)Mrows * Ee * 2);   // also holds v (untransposed) temporarily
    bf16* vT   = (bf16*)alloc((size_t)Bb * Ee * Kk * 2);

    // casts
    int n1 = Ff * Dd;
    cast_k<<<(n1 + 255) / 256, 256, 0, stream>>>(uv_w, uvwb, n1);
    int n2 = Dd * Ee;
    cast_k<<<(n2 + 255) / 256, 256, 0, stream>>>(o_w, owb, n2);

    // rms-norm
    rmsnorm_k<<<Mrows, 256, 0, stream>>>(x, g, xn);

    // GEMM1: uv = silu(xn @ uv_w^T); split u / v(->agg tmp) / q,k
    gemm_nt<0><<<dim3(Ff / BN, Mrows / BM, 1), 256, 0, stream>>>(
        xn, Dd, 0, uvwb, Dd, 0, Dd / BK,
        u, agg, qb, kb, gamma, beta);

    // transpose v: agg(tmp v)[b][2048][1024] -> vT[b][1024][2048]
    transpose_k<<<dim3(Ee / 64, Kk / 64, Bb), 256, 0, stream>>>(agg, vT);

    // GEMM2: P = relu(q@k^T / sqrt(S))^2
    gemm_nt<1><<<dim3(Kk / BN, Kk / BM, Bb), 256, 0, stream>>>(
        qb, Ss, (long long)Kk * Ss, kb, Ss, (long long)Kk * Ss, Ss / BK,
        P, nullptr, nullptr, nullptr, nullptr, nullptr);

    // GEMM3: agg = u * (P @ vT^T)
    gemm_nt<2><<<dim3(Ee / BN, Kk / BM, Bb), 256, 0, stream>>>(
        P, Kk, (long long)Kk * Kk, vT, Kk, (long long)Ee * Kk, Kk / BK,
        agg, u, nullptr, nullptr, nullptr, nullptr);

    // GEMM4: out = x*res_scale + agg @ o_w^T
    gemm_nt<3><<<dim3(Dd / BN, Mrows / BM, 1), 256, 0, stream>>>(
        agg, Ee, 0, owb, Ee, 0, Ee / BK,
        out, (void*)x, (void*)res_scale, nullptr, nullptr, nullptr);
}

// Round 2
// 469.119 us; speedup vs baseline: 1.7080x; 1.7080x over previous
//
#include <hip/hip_runtime.h>
#include <hip/hip_bf16.h>

typedef short bf16x8 __attribute__((ext_vector_type(8)));
typedef float f32x4 __attribute__((ext_vector_type(4)));
using bf16 = __hip_bfloat16;

#define Bb 8
#define Kk 2048
#define Dd 512
#define Ee 1024
#define Ss 128
#define Mrows (Bb*Kk)
#define Ff (2*Ee+Ss)

#define BM 128
#define BN 128
#define BK 64
#define LDK 72   // 64 + 8 pad

#define KVB 64   // kv step in fused attention

static __device__ __forceinline__ float bf2f(bf16 v){ return __bfloat162float(v); }
static __device__ __forceinline__ bf16 f2bf(float v){ return __float2bfloat16(v); }

// ---------------- cast f32 -> bf16 ----------------
__global__ void cast_k(const float* __restrict__ in, bf16* __restrict__ out, int n) {
    int i = blockIdx.x * blockDim.x + threadIdx.x;
    if (i < n) out[i] = f2bf(in[i]);
}

// ---------------- RMS-norm-like ----------------
__global__ __launch_bounds__(256) void rmsnorm_k(const float* __restrict__ x,
                                                 const float* __restrict__ g,
                                                 bf16* __restrict__ xn) {
    int row = blockIdx.x;
    int t = threadIdx.x;
    const float2* xr = (const float2*)(x + (size_t)row * Dd);
    float2 v = xr[t];
    float ss = v.x * v.x + v.y * v.y;
    #pragma unroll
    for (int off = 32; off; off >>= 1) ss += __shfl_down(ss, off);
    __shared__ float red[4];
    if ((t & 63) == 0) red[t >> 6] = ss;
    __syncthreads();
    float tot = red[0] + red[1] + red[2] + red[3];
    float norm = sqrtf(tot * (1.0f / Dd));
    float scale = g[0] / fmaxf(norm, 1e-5f);
    bf16* o = xn + (size_t)row * Dd;
    o[2 * t]     = f2bf(v.x * scale);
    o[2 * t + 1] = f2bf(v.y * scale);
}

// ---------------- 64x64 tile transpose ----------------
__global__ __launch_bounds__(256) void transpose_k(const bf16* __restrict__ in, bf16* __restrict__ out) {
    __shared__ bf16 tile[64][66];
    int e0 = blockIdx.x * 64, j0 = blockIdx.y * 64, b = blockIdx.z;
    const bf16* ib = in  + (size_t)b * Kk * Ee;
    bf16*       ob = out + (size_t)b * Ee * Kk;
    int t = threadIdx.x;
    #pragma unroll
    for (int it = 0; it < 16; ++it) {
        int idx = t + it * 256;
        int j = idx >> 6, e = idx & 63;
        tile[j][e] = ib[(size_t)(j0 + j) * Ee + e0 + e];
    }
    __syncthreads();
    #pragma unroll
    for (int it = 0; it < 16; ++it) {
        int idx = t + it * 256;
        int e = idx >> 6, j = idx & 63;
        ob[(size_t)(e0 + e) * Kk + j0 + j] = tile[j][e];
    }
}

// ---------------- generic NT GEMM (EPI 0: GEMM1 split, EPI 3: GEMM4+residual) ----------------
template<int EPI>
__global__ __launch_bounds__(256, 2)
void gemm_nt(const bf16* __restrict__ A, int lda, long long sA,
             const bf16* __restrict__ B, int ldb, long long sB, int nk,
             void* __restrict__ o0, void* __restrict__ o1,
             void* __restrict__ o2, void* __restrict__ o3,
             const float* __restrict__ gamma, const float* __restrict__ beta) {
    __shared__ bf16 As[BM][LDK];
    __shared__ bf16 Bs[BN][LDK];

    const int t  = threadIdx.x;
    const int bz = blockIdx.z;
    const int tM = blockIdx.y, tN = blockIdx.x;
    const bf16* Ab = A + (size_t)bz * sA + (size_t)tM * BM * lda;
    const bf16* Bp = B + (size_t)bz * sB + (size_t)tN * BN * ldb;

    int r_[4], kc_[4];
    #pragma unroll
    for (int it = 0; it < 4; ++it) { int c = t + it * 256; r_[it] = c >> 3; kc_[it] = (c & 7) * 8; }

    int4 ra[4], rb[4];
    #pragma unroll
    for (int it = 0; it < 4; ++it) {
        ra[it] = *(const int4*)(Ab + (size_t)r_[it] * lda + kc_[it]);
        rb[it] = *(const int4*)(Bp + (size_t)r_[it] * ldb + kc_[it]);
    }

    const int lane = t & 63;
    const int wave = t >> 6;
    const int wr = (wave >> 1) * 64, wc = (wave & 1) * 64;
    const int fr = lane & 15;
    const int ko = (lane >> 4) * 8;
    const int q4 = (lane >> 4) * 4;

    f32x4 acc[4][4] = {};

    for (int kt = 0; kt < nk; ++kt) {
        __syncthreads();
        #pragma unroll
        for (int it = 0; it < 4; ++it) {
            *(int4*)&As[r_[it]][kc_[it]] = ra[it];
            *(int4*)&Bs[r_[it]][kc_[it]] = rb[it];
        }
        __syncthreads();
        if (kt + 1 < nk) {
            int koff = (kt + 1) * BK;
            #pragma unroll
            for (int it = 0; it < 4; ++it) {
                ra[it] = *(const int4*)(Ab + (size_t)r_[it] * lda + koff + kc_[it]);
                rb[it] = *(const int4*)(Bp + (size_t)r_[it] * ldb + koff + kc_[it]);
            }
        }
        #pragma unroll
        for (int kk = 0; kk < 2; ++kk) {
            bf16x8 af[4], bv[4];
            #pragma unroll
            for (int m = 0; m < 4; ++m) af[m] = *(const bf16x8*)&As[wr + m * 16 + fr][kk * 32 + ko];
            #pragma unroll
            for (int n = 0; n < 4; ++n) bv[n] = *(const bf16x8*)&Bs[wc + n * 16 + fr][kk * 32 + ko];
            #pragma unroll
            for (int m = 0; m < 4; ++m)
                #pragma unroll
                for (int n = 0; n < 4; ++n)
                    acc[m][n] = __builtin_amdgcn_mfma_f32_16x16x32_bf16(af[m], bv[n], acc[m][n], 0, 0, 0);
        }
    }

    const int row0 = tM * BM + wr + q4;
    const int col0 = tN * BN + wc + fr;

    #pragma unroll
    for (int m = 0; m < 4; ++m) {
        #pragma unroll
        for (int n = 0; n < 4; ++n) {
            #pragma unroll
            for (int j = 0; j < 4; ++j) {
                float val = acc[m][n][j];
                int rrow = row0 + m * 16 + j;
                int ccol = col0 + n * 16;
                if (EPI == 0) {
                    float s = val / (1.0f + __expf(-val));   // silu
                    if (ccol < Ee) {
                        ((bf16*)o0)[(size_t)rrow * Ee + ccol] = f2bf(s);
                    } else if (ccol < 2 * Ee) {
                        ((bf16*)o1)[(size_t)rrow * Ee + (ccol - Ee)] = f2bf(s);  // v (untransposed tmp)
                    } else {
                        int si = ccol - 2 * Ee;
                        ((bf16*)o2)[(size_t)rrow * Ss + si] = f2bf(s * gamma[si]      + beta[si]);
                        ((bf16*)o3)[(size_t)rrow * Ss + si] = f2bf(s * gamma[Ss + si] + beta[Ss + si]);
                    }
                } else {
                    size_t idx = (size_t)rrow * Dd + ccol;
                    ((float*)o0)[idx] = ((const float*)o1)[idx] * ((const float*)o2)[ccol] + val;
                }
            }
        }
    }
}

// ---------------- fused attention: agg = u * (relu(QK^T/sqrt(S))^2 @ V) ----------------
// Grid: 512 blocks (1-D). blk&7 = batch (XCD swizzle: one batch per XCD so K/vT
// panels stay in that XCD's L2). Block = 512 threads = 8 waves.
// q-tile 128 rows x e-tile 256 cols; kv loop step 64.
// LDS union:
//   [0,17408)      Kt[64][136]   K-tile (depth 128, pad 8)
//   [17408,35840)  Pl[128][72]   P tile (kv 64, pad 8)
//   [35840,72704)  Vt[256][72]   V-tile (e rows, kv cols from vT)
//   Q staging [128][136] = 34816 B aliases the front (pre-loop only).
__global__ __launch_bounds__(512)
void attn_fused(const bf16* __restrict__ qg, const bf16* __restrict__ kg,
                const bf16* __restrict__ vTg, const bf16* __restrict__ ug,
                bf16* __restrict__ aggg) {
    __shared__ char smem[72704];
    bf16 (*Qs)[136] = (bf16(*)[136])smem;
    bf16 (*Kt)[136] = (bf16(*)[136])smem;
    bf16 (*Pl)[72]  = (bf16(*)[72])(smem + 17408);
    bf16 (*Vt)[72]  = (bf16(*)[72])(smem + 35840);

    const int blk = blockIdx.x;
    const int b  = blk & 7;          // batch -> XCD
    const int t2 = blk >> 3;
    const int tE = t2 & 3;           // e-tile 0..3 (256 cols each)
    const int tQ = t2 >> 2;          // q-tile 0..15 (128 rows each)

    const bf16* Qg = qg  + ((size_t)b * Kk + (size_t)tQ * BM) * Ss;
    const bf16* Kg = kg  + (size_t)b * Kk * Ss;
    const bf16* Vg = vTg + (size_t)b * Ee * Kk + (size_t)(tE * 256) * Kk;

    const int t = threadIdx.x;
    const int lane = t & 63, wave = t >> 6;
    const int fr = lane & 15;
    const int ko = (lane >> 4) * 8;
    const int q4 = (lane >> 4) * 4;

    // ---- stage Q [128][128] -> Qs (2048 int4, 4 per thread)
    #pragma unroll
    for (int it = 0; it < 4; ++it) {
        int idx = t + it * 512;
        int r = idx >> 4, c = (idx & 15) * 8;
        *(int4*)&Qs[r][c] = *(const int4*)(Qg + (size_t)r * Ss + c);
    }
    __syncthreads();
    // wave owns S-phase q-rows [wave*16, wave*16+16)
    bf16x8 qf[4];
    #pragma unroll
    for (int ks = 0; ks < 4; ++ks) qf[ks] = *(const bf16x8*)&Qs[wave * 16 + fr][ks * 32 + ko];
    __syncthreads();   // Qs dead; region reused as Kt/Pl below

    // O-phase wave layout: 2 (rows) x 4 (cols)
    const int wm = wave >> 2, wn = wave & 3;
    f32x4 acc[4][4] = {};

    for (int kv = 0; kv < Kk / KVB; ++kv) {
        const bf16* Kgt = Kg + (size_t)kv * KVB * Ss;
        const bf16* Vgt = Vg + (size_t)kv * KVB;
        // stage K [64][128]: 1024 int4, 2/thread
        #pragma unroll
        for (int it = 0; it < 2; ++it) {
            int idx = t + it * 512;
            int r = idx >> 4, c = (idx & 15) * 8;
            *(int4*)&Kt[r][c] = *(const int4*)(Kgt + (size_t)r * Ss + c);
        }
        // stage V [256 e][64 kv]: 2048 int4, 4/thread
        #pragma unroll
        for (int it = 0; it < 4; ++it) {
            int idx = t + it * 512;
            int r = idx >> 3, c = (idx & 7) * 8;
            *(int4*)&Vt[r][c] = *(const int4*)(Vgt + (size_t)r * Kk + c);
        }
        __syncthreads();

        // ---- S-phase: S[wave stripe 16][64] = Q @ K^T (depth 128)
        f32x4 accS[4] = {};
        #pragma unroll
        for (int n = 0; n < 4; ++n) {
            #pragma unroll
            for (int ks = 0; ks < 4; ++ks) {
                bf16x8 kf = *(const bf16x8*)&Kt[n * 16 + fr][ks * 32 + ko];
                accS[n] = __builtin_amdgcn_mfma_f32_16x16x32_bf16(qf[ks], kf, accS[n], 0, 0, 0);
            }
        }
        // relu^2 -> P LDS (bf16)
        #pragma unroll
        for (int n = 0; n < 4; ++n) {
            #pragma unroll
            for (int j = 0; j < 4; ++j) {
                float sc = accS[n][j] * 0.08838834764831845f;  // 1/sqrt(128)
                float r = fmaxf(sc, 0.0f);
                Pl[wave * 16 + q4 + j][n * 16 + fr] = f2bf(r * r);
            }
        }
        __syncthreads();

        // ---- O-phase: acc += P[128][64] @ V[64][256]
        #pragma unroll
        for (int kk = 0; kk < 2; ++kk) {
            bf16x8 af[4], bv[4];
            #pragma unroll
            for (int m = 0; m < 4; ++m) af[m] = *(const bf16x8*)&Pl[wm * 64 + m * 16 + fr][kk * 32 + ko];
            #pragma unroll
            for (int n = 0; n < 4; ++n) bv[n] = *(const bf16x8*)&Vt[wn * 64 + n * 16 + fr][kk * 32 + ko];
            #pragma unroll
            for (int m = 0; m < 4; ++m)
                #pragma unroll
                for (int n = 0; n < 4; ++n)
                    acc[m][n] = __builtin_amdgcn_mfma_f32_16x16x32_bf16(af[m], bv[n], acc[m][n], 0, 0, 0);
        }
        __syncthreads();   // protect Kt/Vt/Pl before next staging
    }

    // ---- epilogue: agg = acc * u
    const size_t rowbase = (size_t)b * Kk + (size_t)tQ * BM;
    #pragma unroll
    for (int m = 0; m < 4; ++m) {
        #pragma unroll
        for (int n = 0; n < 4; ++n) {
            #pragma unroll
            for (int j = 0; j < 4; ++j) {
                int rr = wm * 64 + m * 16 + q4 + j;
                int cc = tE * 256 + wn * 64 + n * 16 + fr;
                size_t idx = (rowbase + rr) * Ee + cc;
                aggg[idx] = f2bf(acc[m][n][j] * bf2f(ug[idx]));
            }
        }
    }
}

extern "C" void kernel_launch(void* const* d_in, const int* in_sizes, int n_in,
                              void* d_out, int out_size, void* d_ws, size_t ws_size,
                              hipStream_t stream) {
    const float* x         = (const float*)d_in[0];
    const float* uv_w      = (const float*)d_in[1];
    const float* o_w       = (const float*)d_in[2];
    const float* gamma     = (const float*)d_in[3];
    const float* beta      = (const float*)d_in[4];
    const float* g         = (const float*)d_in[5];
    const float* res_scale = (const float*)d_in[6];
    float* out = (float*)d_out;

    char* ws = (char*)d_ws;
    size_t off = 0;
    auto alloc = [&](size_t bytes) { void* p = ws + off; off += (bytes + 255) & ~(size_t)255; return p; };

    bf16* xn   = (bf16*)alloc((size_t)Mrows * Dd * 2);
    bf16* uvwb = (bf16*)alloc((size_t)Ff * Dd * 2);
    bf16* owb  = (bf16*)alloc((size_t)Dd * Ee * 2);
    bf16* u    = (bf16*)alloc((size_t)Mrows * Ee * 2);
    bf16* qb   = (bf16*)alloc((size_t)Mrows * Ss * 2);
    bf16* kb   = (bf16*)alloc((size_t)Mrows * Ss * 2);
    bf16* agg  = (bf16*)alloc((size_t)Mrows * Ee * 2);   // also holds v (untransposed) temporarily
    bf16* vT   = (bf16*)alloc((size_t)Bb * Ee * Kk * 2);

    // casts
    int n1 = Ff * Dd;
    cast_k<<<(n1 + 255) / 256, 256, 0, stream>>>(uv_w, uvwb, n1);
    int n2 = Dd * Ee;
    cast_k<<<(n2 + 255) / 256, 256, 0, stream>>>(o_w, owb, n2);

    // rms-norm
    rmsnorm_k<<<Mrows, 256, 0, stream>>>(x, g, xn);

    // GEMM1: uv = silu(xn @ uv_w^T); split u / v(->agg tmp) / q,k
    gemm_nt<0><<<dim3(Ff / BN, Mrows / BM, 1), 256, 0, stream>>>(
        xn, Dd, 0, uvwb, Dd, 0, Dd / BK,
        u, agg, qb, kb, gamma, beta);

    // transpose v: agg(tmp v)[b][2048][1024] -> vT[b][1024][2048]
    transpose_k<<<dim3(Ee / 64, Kk / 64, Bb), 256, 0, stream>>>(agg, vT);

    // fused attention: agg = u * (relu(q k^T / sqrt(S))^2 @ v)
    attn_fused<<<512, 512, 0, stream>>>(qb, kb, vT, u, agg);

    // GEMM4: out = x*res_scale + agg @ o_w^T
    gemm_nt<3><<<dim3(Dd / BN, Mrows / BM, 1), 256, 0, stream>>>(
        agg, Ee, 0, owb, Ee, 0, Ee / BK,
        out, (void*)x, (void*)res_scale, nullptr, nullptr, nullptr);
}

// Round 3
// 279.924 us; speedup vs baseline: 2.8624x; 1.6759x over previous
//
#include <hip/hip_runtime.h>
#include <hip/hip_bf16.h>

typedef short bf16x8 __attribute__((ext_vector_type(8)));
typedef float f32x4 __attribute__((ext_vector_type(4)));
using bf16 = __hip_bfloat16;

#define Bb 8
#define Kk 2048
#define Dd 512
#define Ee 1024
#define Ss 128
#define Mrows (Bb*Kk)
#define Ff (2*Ee+Ss)

#define BM 128
#define BN 128
#define BK 64

#define KVB 64

static __device__ __forceinline__ float bf2f(bf16 v){ return __bfloat162float(v); }
static __device__ __forceinline__ bf16 f2bf(float v){ return __float2bfloat16(v); }

static __device__ __forceinline__ void gload16(const bf16* g, bf16* l) {
    __builtin_amdgcn_global_load_lds((const __attribute__((address_space(1))) void*)g,
                                     (__attribute__((address_space(3))) void*)l, 16, 0, 0);
}

union BV { int4 v; bf16 h[8]; };

// ---------------- cast f32 -> bf16 ----------------
__global__ void cast_k(const float* __restrict__ in, bf16* __restrict__ out, int n) {
    int i = blockIdx.x * blockDim.x + threadIdx.x;
    if (i < n) out[i] = f2bf(in[i]);
}

// ---------------- RMS-norm-like ----------------
__global__ __launch_bounds__(256) void rmsnorm_k(const float* __restrict__ x,
                                                 const float* __restrict__ g,
                                                 bf16* __restrict__ xn) {
    int row = blockIdx.x;
    int t = threadIdx.x;
    const float2* xr = (const float2*)(x + (size_t)row * Dd);
    float2 v = xr[t];
    float ss = v.x * v.x + v.y * v.y;
    #pragma unroll
    for (int off = 32; off; off >>= 1) ss += __shfl_down(ss, off);
    __shared__ float red[4];
    if ((t & 63) == 0) red[t >> 6] = ss;
    __syncthreads();
    float tot = red[0] + red[1] + red[2] + red[3];
    float norm = sqrtf(tot * (1.0f / Dd));
    float scale = g[0] / fmaxf(norm, 1e-5f);
    bf16* o = xn + (size_t)row * Dd;
    o[2 * t]     = f2bf(v.x * scale);
    o[2 * t + 1] = f2bf(v.y * scale);
}

// ---------------- GEMM (m97-style: global_load_lds, linear LDS, double-buffered) ----------------
// EPI 0 (GEMM1): silu epilogue, split u / vT (transposed in-LDS) / q,k (gamma,beta)
// EPI 3 (GEMM4): out = x*res_scale + acc (f32), coalesced float4
// Grid is 1-D; bid&7 = XCD; each XCD owns 16 consecutive row panels so A panels
// are fetched once per chip and B stays L2-resident.
template<int EPI>
__global__ __launch_bounds__(256, 2)
void gemm_nt(const bf16* __restrict__ A, int lda,
             const bf16* __restrict__ B, int ldb, int nk, int nTN,
             bf16* __restrict__ u, bf16* __restrict__ vT,
             bf16* __restrict__ qb, bf16* __restrict__ kb,
             const float* __restrict__ gamma, const float* __restrict__ beta,
             const float* __restrict__ x, const float* __restrict__ rsc,
             float* __restrict__ out) {
    __shared__ char smem[65536];   // 2 bufs x (A 16K + B 16K); reused by epilogue

    const int t = threadIdx.x;
    const int bid = blockIdx.x;
    const int xcd = bid & 7;
    const int ii  = bid >> 3;
    const int tM = xcd * 16 + ii / nTN;
    const int tN = ii % nTN;
    const int rowM = tM * BM;

    const bf16* Ab = A + (size_t)rowM * lda;
    const bf16* Bp = B + (size_t)tN * BN * ldb;

    const int lane = t & 63;
    const int wave = t >> 6;
    const int wr = (wave >> 1) * 64, wc = (wave & 1) * 64;
    const int fr = lane & 15;
    const int ko = (lane >> 4) * 8;
    const int q4 = (lane >> 4) * 4;

    auto stage = [&](int buf, int k0) {
        bf16* Al = (bf16*)(smem + buf * 32768);
        bf16* Bl = Al + 8192;
        #pragma unroll
        for (int it = 0; it < 4; ++it) {
            int idx = t + it * 256;
            int r = idx >> 3, c = (idx & 7) * 8;
            gload16(Ab + (size_t)r * lda + k0 + c, Al + idx * 8);
            gload16(Bp + (size_t)r * ldb + k0 + c, Bl + idx * 8);
        }
    };

    f32x4 acc[4][4] = {};
    int cur = 0;
    stage(0, 0);
    for (int kt = 0; kt < nk; ++kt) {
        __syncthreads();                       // drains vmcnt -> buf[cur] ready
        if (kt + 1 < nk) stage(cur ^ 1, (kt + 1) * BK);
        const bf16* Asl = (const bf16*)(smem + cur * 32768);
        const bf16* Bsl = Asl + 8192;
        #pragma unroll
        for (int kk = 0; kk < 2; ++kk) {
            bf16x8 af[4], bv[4];
            #pragma unroll
            for (int m = 0; m < 4; ++m) af[m] = *(const bf16x8*)&Asl[(wr + m * 16 + fr) * BK + kk * 32 + ko];
            #pragma unroll
            for (int n = 0; n < 4; ++n) bv[n] = *(const bf16x8*)&Bsl[(wc + n * 16 + fr) * BK + kk * 32 + ko];
            #pragma unroll
            for (int m = 0; m < 4; ++m)
                #pragma unroll
                for (int n = 0; n < 4; ++n)
                    acc[m][n] = __builtin_amdgcn_mfma_f32_16x16x32_bf16(af[m], bv[n], acc[m][n], 0, 0, 0);
        }
        cur ^= 1;
    }
    __syncthreads();   // LDS free for epilogue staging

    if (EPI == 0) {
        bf16 (*Ot)[140] = (bf16(*)[140])smem;      // 128x140x2 = 35840 B
        const bool isV = (tN >= 8 && tN < 16);
        #pragma unroll
        for (int m = 0; m < 4; ++m)
            #pragma unroll
            for (int n = 0; n < 4; ++n)
                #pragma unroll
                for (int j = 0; j < 4; ++j) {
                    float val = acc[m][n][j];
                    float s = val / (1.0f + __expf(-val));
                    int rr = wr + m * 16 + q4 + j;
                    int cc = wc + n * 16 + fr;
                    if (isV) Ot[cc][rr] = f2bf(s);   // transposed stage for vT
                    else     Ot[rr][cc] = f2bf(s);
                }
        __syncthreads();
        if (tN < 8) {                                 // ---- u region
            bf16* dst = u + (size_t)rowM * Ee + tN * 128;
            #pragma unroll
            for (int i = 0; i < 8; ++i) {
                int r = wave * 32 + (lane >> 4) + i * 4;
                int c = (lane & 15) * 8;
                *(int4*)&dst[(size_t)r * Ee + c] = *(const int4*)&Ot[r][c];
            }
        } else if (tN < 16) {                         // ---- v region -> vT directly
            int b  = rowM >> 11;                       // rowM / 2048
            int j0 = rowM & 2047;
            bf16* dst = vT + (size_t)b * Ee * Kk + (size_t)(tN - 8) * 128 * Kk + j0;
            #pragma unroll
            for (int i = 0; i < 8; ++i) {
                int e = wave * 32 + (lane >> 4) + i * 4;  // tile col (e dim)
                int c = (lane & 15) * 8;                  // row chunk (j dim)
                *(int4*)&dst[(size_t)e * Kk + c] = *(const int4*)&Ot[e][c];
            }
        } else {                                      // ---- q/k region
            #pragma unroll
            for (int i = 0; i < 8; ++i) {
                int r = wave * 32 + (lane >> 4) + i * 4;
                int c = (lane & 15) * 8;
                BV sv; sv.v = *(const int4*)&Ot[r][c];
                BV qv, kv;
                #pragma unroll
                for (int e2 = 0; e2 < 8; ++e2) {
                    float s = bf2f(sv.h[e2]);
                    qv.h[e2] = f2bf(s * gamma[c + e2]       + beta[c + e2]);
                    kv.h[e2] = f2bf(s * gamma[128 + c + e2] + beta[128 + c + e2]);
                }
                *(int4*)&qb[(size_t)(rowM + r) * Ss + c] = qv.v;
                *(int4*)&kb[(size_t)(rowM + r) * Ss + c] = kv.v;
            }
        }
    } else {
        float (*Of)[134] = (float(*)[134])smem;    // 64x134x4 = 34304 B
        const int col0 = tN * 128;
        #pragma unroll
        for (int h = 0; h < 2; ++h) {
            if (h) __syncthreads();
            if ((wave >> 1) == h) {
                #pragma unroll
                for (int m = 0; m < 4; ++m)
                    #pragma unroll
                    for (int n = 0; n < 4; ++n)
                        #pragma unroll
                        for (int j = 0; j < 4; ++j)
                            Of[m * 16 + q4 + j][wc + n * 16 + fr] = acc[m][n][j];
            }
            __syncthreads();
            #pragma unroll
            for (int i = 0; i < 8; ++i) {
                int idx = t + i * 256;
                int r = idx >> 5, c4 = (idx & 31) * 4;
                size_t row = (size_t)(rowM + h * 64 + r);
                float4 v  = *(const float4*)&Of[r][c4];
                float4 xv = *(const float4*)&x[row * Dd + col0 + c4];
                float4 rv = *(const float4*)&rsc[col0 + c4];
                float4 o;
                o.x = xv.x * rv.x + v.x;  o.y = xv.y * rv.y + v.y;
                o.z = xv.z * rv.z + v.z;  o.w = xv.w * rv.w + v.w;
                *(float4*)&out[row * Dd + col0 + c4] = o;
            }
        }
    }
}

// ---------------- fused attention: agg = u * (relu(QK^T/sqrt(S))^2 @ V) ----------------
__global__ __launch_bounds__(512)
void attn_fused(const bf16* __restrict__ qg, const bf16* __restrict__ kg,
                const bf16* __restrict__ vTg, const bf16* __restrict__ ug,
                bf16* __restrict__ aggg) {
    __shared__ char smem[72704];
    bf16 (*Qs)[136] = (bf16(*)[136])smem;
    bf16 (*Kt)[136] = (bf16(*)[136])smem;
    bf16 (*Pl)[72]  = (bf16(*)[72])(smem + 17408);
    bf16 (*Vt)[72]  = (bf16(*)[72])(smem + 35840);

    const int blk = blockIdx.x;
    const int b  = blk & 7;
    const int t2 = blk >> 3;
    const int tE = t2 & 3;
    const int tQ = t2 >> 2;

    const bf16* Qg = qg  + ((size_t)b * Kk + (size_t)tQ * BM) * Ss;
    const bf16* Kg = kg  + (size_t)b * Kk * Ss;
    const bf16* Vg = vTg + (size_t)b * Ee * Kk + (size_t)(tE * 256) * Kk;

    const int t = threadIdx.x;
    const int lane = t & 63, wave = t >> 6;
    const int fr = lane & 15;
    const int ko = (lane >> 4) * 8;
    const int q4 = (lane >> 4) * 4;

    #pragma unroll
    for (int it = 0; it < 4; ++it) {
        int idx = t + it * 512;
        int r = idx >> 4, c = (idx & 15) * 8;
        *(int4*)&Qs[r][c] = *(const int4*)(Qg + (size_t)r * Ss + c);
    }
    __syncthreads();
    bf16x8 qf[4];
    #pragma unroll
    for (int ks = 0; ks < 4; ++ks) qf[ks] = *(const bf16x8*)&Qs[wave * 16 + fr][ks * 32 + ko];
    __syncthreads();

    const int wm = wave >> 2, wn = wave & 3;
    f32x4 acc[4][4] = {};

    for (int kv = 0; kv < Kk / KVB; ++kv) {
        const bf16* Kgt = Kg + (size_t)kv * KVB * Ss;
        const bf16* Vgt = Vg + (size_t)kv * KVB;
        #pragma unroll
        for (int it = 0; it < 2; ++it) {
            int idx = t + it * 512;
            int r = idx >> 4, c = (idx & 15) * 8;
            *(int4*)&Kt[r][c] = *(const int4*)(Kgt + (size_t)r * Ss + c);
        }
        #pragma unroll
        for (int it = 0; it < 4; ++it) {
            int idx = t + it * 512;
            int r = idx >> 3, c = (idx & 7) * 8;
            *(int4*)&Vt[r][c] = *(const int4*)(Vgt + (size_t)r * Kk + c);
        }
        __syncthreads();

        f32x4 accS[4] = {};
        #pragma unroll
        for (int n = 0; n < 4; ++n) {
            #pragma unroll
            for (int ks = 0; ks < 4; ++ks) {
                bf16x8 kf = *(const bf16x8*)&Kt[n * 16 + fr][ks * 32 + ko];
                accS[n] = __builtin_amdgcn_mfma_f32_16x16x32_bf16(qf[ks], kf, accS[n], 0, 0, 0);
            }
        }
        #pragma unroll
        for (int n = 0; n < 4; ++n) {
            #pragma unroll
            for (int j = 0; j < 4; ++j) {
                float sc = accS[n][j] * 0.08838834764831845f;
                float r = fmaxf(sc, 0.0f);
                Pl[wave * 16 + q4 + j][n * 16 + fr] = f2bf(r * r);
            }
        }
        __syncthreads();

        #pragma unroll
        for (int kk = 0; kk < 2; ++kk) {
            bf16x8 af[4], bv[4];
            #pragma unroll
            for (int m = 0; m < 4; ++m) af[m] = *(const bf16x8*)&Pl[wm * 64 + m * 16 + fr][kk * 32 + ko];
            #pragma unroll
            for (int n = 0; n < 4; ++n) bv[n] = *(const bf16x8*)&Vt[wn * 64 + n * 16 + fr][kk * 32 + ko];
            #pragma unroll
            for (int m = 0; m < 4; ++m)
                #pragma unroll
                for (int n = 0; n < 4; ++n)
                    acc[m][n] = __builtin_amdgcn_mfma_f32_16x16x32_bf16(af[m], bv[n], acc[m][n], 0, 0, 0);
        }
        __syncthreads();
    }

    // ---- LDS-staged coalesced epilogue: agg = acc * u
    bf16 (*Ot)[264] = (bf16(*)[264])smem;        // 128x264x2 = 67584 <= 72704
    #pragma unroll
    for (int m = 0; m < 4; ++m)
        #pragma unroll
        for (int n = 0; n < 4; ++n)
            #pragma unroll
            for (int j = 0; j < 4; ++j)
                Ot[wm * 64 + m * 16 + q4 + j][wn * 64 + n * 16 + fr] = f2bf(acc[m][n][j]);
    __syncthreads();

    const size_t rowbase = (size_t)b * Kk + (size_t)tQ * BM;
    const bf16* usrc = ug   + rowbase * Ee + tE * 256;
    bf16*       adst = aggg + rowbase * Ee + tE * 256;
    #pragma unroll
    for (int i = 0; i < 8; ++i) {
        int idx = t + i * 512;
        int r = idx >> 5, c = (idx & 31) * 8;
        BV ov, uv2, rv;
        ov.v  = *(const int4*)&Ot[r][c];
        uv2.v = *(const int4*)&usrc[(size_t)r * Ee + c];
        #pragma unroll
        for (int e2 = 0; e2 < 8; ++e2) rv.h[e2] = f2bf(bf2f(ov.h[e2]) * bf2f(uv2.h[e2]));
        *(int4*)&adst[(size_t)r * Ee + c] = rv.v;
    }
}

extern "C" void kernel_launch(void* const* d_in, const int* in_sizes, int n_in,
                              void* d_out, int out_size, void* d_ws, size_t ws_size,
                              hipStream_t stream) {
    const float* x         = (const float*)d_in[0];
    const float* uv_w      = (const float*)d_in[1];
    const float* o_w       = (const float*)d_in[2];
    const float* gamma     = (const float*)d_in[3];
    const float* beta      = (const float*)d_in[4];
    const float* g         = (const float*)d_in[5];
    const float* res_scale = (const float*)d_in[6];
    float* out = (float*)d_out;

    char* ws = (char*)d_ws;
    size_t off = 0;
    auto alloc = [&](size_t bytes) { void* p = ws + off; off += (bytes + 255) & ~(size_t)255; return p; };

    bf16* xn   = (bf16*)alloc((size_t)Mrows * Dd * 2);
    bf16* uvwb = (bf16*)alloc((size_t)Ff * Dd * 2);
    bf16* owb  = (bf16*)alloc((size_t)Dd * Ee * 2);
    bf16* u    = (bf16*)alloc((size_t)Mrows * Ee * 2);
    bf16* qb   = (bf16*)alloc((size_t)Mrows * Ss * 2);
    bf16* kb   = (bf16*)alloc((size_t)Mrows * Ss * 2);
    bf16* agg  = (bf16*)alloc((size_t)Mrows * Ee * 2);
    bf16* vT   = (bf16*)alloc((size_t)Bb * Ee * Kk * 2);

    int n1 = Ff * Dd;
    cast_k<<<(n1 + 255) / 256, 256, 0, stream>>>(uv_w, uvwb, n1);
    int n2 = Dd * Ee;
    cast_k<<<(n2 + 255) / 256, 256, 0, stream>>>(o_w, owb, n2);

    rmsnorm_k<<<Mrows, 256, 0, stream>>>(x, g, xn);

    // GEMM1: silu(xn @ uv_w^T) -> u, vT (transposed), q, k.  grid 17*128 = 2176
    gemm_nt<0><<<2176, 256, 0, stream>>>(
        xn, Dd, uvwb, Dd, Dd / BK, 17,
        u, vT, qb, kb, gamma, beta, nullptr, nullptr, nullptr);

    // fused attention
    attn_fused<<<512, 512, 0, stream>>>(qb, kb, vT, u, agg);

    // GEMM4: out = x*res_scale + agg @ o_w^T.  grid 4*128 = 512
    gemm_nt<3><<<512, 256, 0, stream>>>(
        agg, Ee, owb, Ee, Ee / BK, 4,
        nullptr, nullptr, nullptr, nullptr, nullptr, nullptr,
        x, res_scale, out);
}

// Round 4
// 217.855 us; speedup vs baseline: 3.6780x; 1.2849x over previous
//
#include <hip/hip_runtime.h>
#include <hip/hip_bf16.h>

typedef short bf16x8 __attribute__((ext_vector_type(8)));
typedef float f32x4 __attribute__((ext_vector_type(4)));
using bf16 = __hip_bfloat16;

#define Bb 8
#define Kk 2048
#define Dd 512
#define Ee 1024
#define Ss 128
#define Mrows (Bb*Kk)
#define Ff (2*Ee+Ss)

#define BM 128
#define BN 128
#define BK 64

#define KVB 64

static __device__ __forceinline__ float bf2f(bf16 v){ return __bfloat162float(v); }
static __device__ __forceinline__ bf16 f2bf(float v){ return __float2bfloat16(v); }
static __device__ __forceinline__ unsigned short bfbits(float v){ bf16 b = __float2bfloat16(v); return *(unsigned short*)&b; }

static __device__ __forceinline__ void gload16(const bf16* g, bf16* l) {
    __builtin_amdgcn_global_load_lds((const __attribute__((address_space(1))) void*)g,
                                     (__attribute__((address_space(3))) void*)l, 16, 0, 0);
}

union BV { int4 v; bf16 h[8]; };

// ---------------- cast f32 -> bf16 ----------------
__global__ void cast_k(const float* __restrict__ in, bf16* __restrict__ out, int n) {
    int i = blockIdx.x * blockDim.x + threadIdx.x;
    if (i < n) out[i] = f2bf(in[i]);
}

// ---------------- RMS-norm-like ----------------
__global__ __launch_bounds__(256) void rmsnorm_k(const float* __restrict__ x,
                                                 const float* __restrict__ g,
                                                 bf16* __restrict__ xn) {
    int row = blockIdx.x;
    int t = threadIdx.x;
    const float2* xr = (const float2*)(x + (size_t)row * Dd);
    float2 v = xr[t];
    float ss = v.x * v.x + v.y * v.y;
    #pragma unroll
    for (int off = 32; off; off >>= 1) ss += __shfl_down(ss, off);
    __shared__ float red[4];
    if ((t & 63) == 0) red[t >> 6] = ss;
    __syncthreads();
    float tot = red[0] + red[1] + red[2] + red[3];
    float norm = sqrtf(tot * (1.0f / Dd));
    float scale = g[0] / fmaxf(norm, 1e-5f);
    bf16* o = xn + (size_t)row * Dd;
    o[2 * t]     = f2bf(v.x * scale);
    o[2 * t + 1] = f2bf(v.y * scale);
}

// ---------------- GEMM (global_load_lds, linear LDS + XOR swizzle, dbuf) ----------------
template<int EPI>
__global__ __launch_bounds__(256, 2)
void gemm_nt(const bf16* __restrict__ A, int lda,
             const bf16* __restrict__ B, int ldb, int nk, int nTN,
             bf16* __restrict__ u, bf16* __restrict__ vT,
             bf16* __restrict__ qb, bf16* __restrict__ kb,
             const float* __restrict__ gamma, const float* __restrict__ beta,
             const float* __restrict__ x, const float* __restrict__ rsc,
             float* __restrict__ out) {
    __shared__ char smem[65536];   // 2 bufs x (A 16K + B 16K); reused by epilogue

    const int t = threadIdx.x;
    const int bid = blockIdx.x;
    const int xcd = bid & 7;
    const int ii  = bid >> 3;
    const int tM = xcd * 16 + ii / nTN;
    const int tN = ii % nTN;
    const int rowM = tM * BM;

    const bf16* Ab = A + (size_t)rowM * lda;
    const bf16* Bp = B + (size_t)tN * BN * ldb;

    const int lane = t & 63;
    const int wave = t >> 6;
    const int wr = (wave >> 1) * 64, wc = (wave & 1) * 64;
    const int fr = lane & 15;
    const int h  = lane >> 4;
    const int ko = h * 8;
    const int q4 = h * 4;

    // staging: slot (r, c') in linear [128][64]; fetch global chunk c'^(r&7)
    auto stage = [&](int buf, int k0) {
        bf16* Al = (bf16*)(smem + buf * 32768);
        bf16* Bl = Al + 8192;
        #pragma unroll
        for (int it = 0; it < 4; ++it) {
            int idx = t + it * 256;
            int r = idx >> 3, cp = idx & 7;
            int cg = (cp ^ r) & 7;
            gload16(Ab + (size_t)r * lda + k0 + cg * 8, Al + idx * 8);
            gload16(Bp + (size_t)r * ldb + k0 + cg * 8, Bl + idx * 8);
        }
    };

    f32x4 acc[4][4] = {};
    int cur = 0;
    stage(0, 0);
    for (int kt = 0; kt < nk; ++kt) {
        __syncthreads();
        if (kt + 1 < nk) stage(cur ^ 1, (kt + 1) * BK);
        const bf16* Asl = (const bf16*)(smem + cur * 32768);
        const bf16* Bsl = Asl + 8192;
        #pragma unroll
        for (int kk = 0; kk < 2; ++kk) {
            const int cs = ((4 * kk + h) ^ (fr & 7)) * 8;   // swizzled chunk
            bf16x8 af[4], bv[4];
            #pragma unroll
            for (int m = 0; m < 4; ++m) af[m] = *(const bf16x8*)&Asl[(wr + m * 16 + fr) * BK + cs];
            #pragma unroll
            for (int n = 0; n < 4; ++n) bv[n] = *(const bf16x8*)&Bsl[(wc + n * 16 + fr) * BK + cs];
            #pragma unroll
            for (int m = 0; m < 4; ++m)
                #pragma unroll
                for (int n = 0; n < 4; ++n)
                    acc[m][n] = __builtin_amdgcn_mfma_f32_16x16x32_bf16(af[m], bv[n], acc[m][n], 0, 0, 0);
        }
        cur ^= 1;
    }
    __syncthreads();

    if (EPI == 0) {
        bf16 (*Ot)[140] = (bf16(*)[140])smem;
        const bool isV = (tN >= 8 && tN < 16);
        #pragma unroll
        for (int m = 0; m < 4; ++m)
            #pragma unroll
            for (int n = 0; n < 4; ++n)
                #pragma unroll
                for (int j = 0; j < 4; ++j) {
                    float val = acc[m][n][j];
                    float s = val / (1.0f + __expf(-val));
                    int rr = wr + m * 16 + q4 + j;
                    int cc = wc + n * 16 + fr;
                    if (isV) Ot[cc][rr] = f2bf(s);
                    else     Ot[rr][cc] = f2bf(s);
                }
        __syncthreads();
        if (tN < 8) {
            bf16* dst = u + (size_t)rowM * Ee + tN * 128;
            #pragma unroll
            for (int i = 0; i < 8; ++i) {
                int r = wave * 32 + (lane >> 4) + i * 4;
                int c = (lane & 15) * 8;
                *(int4*)&dst[(size_t)r * Ee + c] = *(const int4*)&Ot[r][c];
            }
        } else if (tN < 16) {
            int b  = rowM >> 11;
            int j0 = rowM & 2047;
            bf16* dst = vT + (size_t)b * Ee * Kk + (size_t)(tN - 8) * 128 * Kk + j0;
            #pragma unroll
            for (int i = 0; i < 8; ++i) {
                int e = wave * 32 + (lane >> 4) + i * 4;
                int c = (lane & 15) * 8;
                *(int4*)&dst[(size_t)e * Kk + c] = *(const int4*)&Ot[e][c];
            }
        } else {
            #pragma unroll
            for (int i = 0; i < 8; ++i) {
                int r = wave * 32 + (lane >> 4) + i * 4;
                int c = (lane & 15) * 8;
                BV sv; sv.v = *(const int4*)&Ot[r][c];
                BV qv, kv;
                #pragma unroll
                for (int e2 = 0; e2 < 8; ++e2) {
                    float s = bf2f(sv.h[e2]);
                    qv.h[e2] = f2bf(s * gamma[c + e2]       + beta[c + e2]);
                    kv.h[e2] = f2bf(s * gamma[128 + c + e2] + beta[128 + c + e2]);
                }
                *(int4*)&qb[(size_t)(rowM + r) * Ss + c] = qv.v;
                *(int4*)&kb[(size_t)(rowM + r) * Ss + c] = kv.v;
            }
        }
    } else {
        float (*Of)[134] = (float(*)[134])smem;
        const int col0 = tN * 128;
        #pragma unroll
        for (int hh = 0; hh < 2; ++hh) {
            if (hh) __syncthreads();
            if ((wave >> 1) == hh) {
                #pragma unroll
                for (int m = 0; m < 4; ++m)
                    #pragma unroll
                    for (int n = 0; n < 4; ++n)
                        #pragma unroll
                        for (int j = 0; j < 4; ++j)
                            Of[m * 16 + q4 + j][wc + n * 16 + fr] = acc[m][n][j];
            }
            __syncthreads();
            #pragma unroll
            for (int i = 0; i < 8; ++i) {
                int idx = t + i * 256;
                int r = idx >> 5, c4 = (idx & 31) * 4;
                size_t row = (size_t)(rowM + hh * 64 + r);
                float4 v  = *(const float4*)&Of[r][c4];
                float4 xv = *(const float4*)&x[row * Dd + col0 + c4];
                float4 rv = *(const float4*)&rsc[col0 + c4];
                float4 o;
                o.x = xv.x * rv.x + v.x;  o.y = xv.y * rv.y + v.y;
                o.z = xv.z * rv.z + v.z;  o.w = xv.w * rv.w + v.w;
                *(float4*)&out[row * Dd + col0 + c4] = o;
            }
        }
    }
}

// ---------------- fused attention: agg = u * (relu(QK^T/sqrt(S))^2 @ V) ----------------
// 512 threads = 8 waves. q-tile 128 x e-tile 256; KVB=64.
// LDS: Kbuf[2][64][128] (32K) | Vbuf[2][256][64] (64K) | Pl[128][72] (18.4K) = 116736 B.
// K/V linear via global_load_lds with inverse-XOR-swizzled global source chunks.
// S-phase: wave = (q-group 32, kv-half 32), swapped mfma(K, Q): 8 K-frag reads/wave.
// P packed-b32 to LDS; PV: wave = (q-half 64, e-quarter 64), acc 4x4.
__global__ __launch_bounds__(512)
void attn_fused(const bf16* __restrict__ qg, const bf16* __restrict__ kg,
                const bf16* __restrict__ vTg, const bf16* __restrict__ ug,
                bf16* __restrict__ aggg) {
    __shared__ char smem[116736];
    bf16* Kbuf = (bf16*)smem;                     // [2][64*128]
    bf16* Vbuf = (bf16*)(smem + 32768);           // [2][256*64]
    bf16 (*Pl)[72] = (bf16(*)[72])(smem + 98304); // [128][72]

    const int blk = blockIdx.x;
    const int b  = blk & 7;
    const int t2 = blk >> 3;
    const int tE = t2 & 3;
    const int tQ = t2 >> 2;

    const bf16* Qp = qg  + ((size_t)b * Kk + (size_t)tQ * BM) * Ss;
    const bf16* Kg = kg  + (size_t)b * Kk * Ss;
    const bf16* Vg = vTg + (size_t)b * Ee * Kk + (size_t)(tE * 256) * Kk;

    const int t = threadIdx.x;
    const int lane = t & 63, wave = t >> 6;
    const int fr = lane & 15;
    const int h  = lane >> 4;
    const int ko = h * 8;
    const int q4 = h * 4;

    // S-phase role: q-group (32 rows) x kv-half (32)
    const int qgp = wave & 3, kvh = wave >> 2;
    // PV role: q-half (64) x e-quarter (64)
    const int wm = wave >> 2, wn = wave & 3;

    // Q fragments straight from global (B-operand): q = 32*qgp + 16*qs + fr
    bf16x8 qf[2][4];
    #pragma unroll
    for (int qs = 0; qs < 2; ++qs)
        #pragma unroll
        for (int ks = 0; ks < 4; ++ks)
            qf[qs][ks] = *(const bf16x8*)(Qp + (size_t)(32 * qgp + 16 * qs + fr) * Ss + 32 * ks + ko);

    auto stage = [&](int buf, int kvt) {
        const bf16* Kgt = Kg + (size_t)kvt * KVB * Ss;
        const bf16* Vgt = Vg + (size_t)kvt * KVB;
        bf16* Kl = Kbuf + buf * 8192;
        bf16* Vl = Vbuf + buf * 16384;
        #pragma unroll
        for (int it = 0; it < 2; ++it) {          // K: 64 rows x 16 chunks
            int idx = t + it * 512;
            int r = idx >> 4, cp = idx & 15;
            int cg = (cp & 8) | ((cp ^ r) & 7);
            gload16(Kgt + (size_t)r * Ss + cg * 8, Kl + idx * 8);
        }
        #pragma unroll
        for (int it = 0; it < 4; ++it) {          // V: 256 rows x 8 chunks
            int idx = t + it * 512;
            int r = idx >> 3, cp = idx & 7;
            int cg = (cp ^ r) & 7;
            gload16(Vgt + (size_t)r * Kk + cg * 8, Vl + idx * 8);
        }
    };

    f32x4 acc[4][4] = {};
    stage(0, 0);

    for (int kv = 0; kv < Kk / KVB; ++kv) {
        const int cur = kv & 1;
        __syncthreads();   // cur staged (drains vmcnt) + prev PV done with Pl/bufs

        // ---- S-phase (swapped): accS[qs][n] = K[32*kvh+16n+..] x Q[32*qgp+16qs+..]
        const bf16* Kl = Kbuf + cur * 8192;
        f32x4 accS[2][2] = {};
        #pragma unroll
        for (int n = 0; n < 2; ++n) {
            #pragma unroll
            for (int ks = 0; ks < 4; ++ks) {
                int c = 4 * ks + h;
                int cs = (c & 8) | ((c ^ fr) & 7);
                bf16x8 af = *(const bf16x8*)&Kl[(32 * kvh + 16 * n + fr) * 128 + cs * 8];
                #pragma unroll
                for (int qs = 0; qs < 2; ++qs)
                    accS[qs][n] = __builtin_amdgcn_mfma_f32_16x16x32_bf16(af, qf[qs][ks], accS[qs][n], 0, 0, 0);
            }
        }
        // relu^2 -> P (packed b32 pairs).  lane holds S[kv=32kvh+16n+q4+j][q=32qgp+16qs+fr]
        #pragma unroll
        for (int qs = 0; qs < 2; ++qs) {
            int rowP = 32 * qgp + 16 * qs + fr;
            #pragma unroll
            for (int n = 0; n < 2; ++n) {
                #pragma unroll
                for (int pr = 0; pr < 2; ++pr) {
                    float s0 = accS[qs][n][2 * pr]     * 0.08838834764831845f;
                    float s1 = accS[qs][n][2 * pr + 1] * 0.08838834764831845f;
                    s0 = fmaxf(s0, 0.0f); s1 = fmaxf(s1, 0.0f);
                    unsigned int w = (unsigned int)bfbits(s0 * s0) | ((unsigned int)bfbits(s1 * s1) << 16);
                    *(unsigned int*)&Pl[rowP][32 * kvh + 16 * n + q4 + 2 * pr] = w;
                }
            }
        }
        __syncthreads();   // P visible

        if (kv + 1 < Kk / KVB) stage(cur ^ 1, kv + 1);   // async, lands under PV + next S

        // ---- PV: acc += P[wm*64..][64kv] @ V[64kv][wn*64..]
        const bf16* Vl = Vbuf + cur * 16384;
        __builtin_amdgcn_s_setprio(1);
        #pragma unroll
        for (int kk = 0; kk < 2; ++kk) {
            const int csv = ((4 * kk + h) ^ (fr & 7)) * 8;
            bf16x8 af[4], bv[4];
            #pragma unroll
            for (int m = 0; m < 4; ++m) af[m] = *(const bf16x8*)&Pl[wm * 64 + m * 16 + fr][kk * 32 + ko];
            #pragma unroll
            for (int n = 0; n < 4; ++n) bv[n] = *(const bf16x8*)&Vl[(wn * 64 + n * 16 + fr) * 64 + csv];
            #pragma unroll
            for (int m = 0; m < 4; ++m)
                #pragma unroll
                for (int n = 0; n < 4; ++n)
                    acc[m][n] = __builtin_amdgcn_mfma_f32_16x16x32_bf16(af[m], bv[n], acc[m][n], 0, 0, 0);
        }
        __builtin_amdgcn_s_setprio(0);
    }
    __syncthreads();

    // ---- LDS-staged coalesced epilogue: agg = acc * u
    bf16 (*Ot)[264] = (bf16(*)[264])smem;
    #pragma unroll
    for (int m = 0; m < 4; ++m)
        #pragma unroll
        for (int n = 0; n < 4; ++n)
            #pragma unroll
            for (int j = 0; j < 4; ++j)
                Ot[wm * 64 + m * 16 + q4 + j][wn * 64 + n * 16 + fr] = f2bf(acc[m][n][j]);
    __syncthreads();

    const size_t rowbase = (size_t)b * Kk + (size_t)tQ * BM;
    const bf16* usrc = ug   + rowbase * Ee + tE * 256;
    bf16*       adst = aggg + rowbase * Ee + tE * 256;
    #pragma unroll
    for (int i = 0; i < 8; ++i) {
        int idx = t + i * 512;
        int r = idx >> 5, c = (idx & 31) * 8;
        BV ov, uv2, rv;
        ov.v  = *(const int4*)&Ot[r][c];
        uv2.v = *(const int4*)&usrc[(size_t)r * Ee + c];
        #pragma unroll
        for (int e2 = 0; e2 < 8; ++e2) rv.h[e2] = f2bf(bf2f(ov.h[e2]) * bf2f(uv2.h[e2]));
        *(int4*)&adst[(size_t)r * Ee + c] = rv.v;
    }
}

extern "C" void kernel_launch(void* const* d_in, const int* in_sizes, int n_in,
                              void* d_out, int out_size, void* d_ws, size_t ws_size,
                              hipStream_t stream) {
    const float* x         = (const float*)d_in[0];
    const float* uv_w      = (const float*)d_in[1];
    const float* o_w       = (const float*)d_in[2];
    const float* gamma     = (const float*)d_in[3];
    const float* beta      = (const float*)d_in[4];
    const float* g         = (const float*)d_in[5];
    const float* res_scale = (const float*)d_in[6];
    float* out = (float*)d_out;

    char* ws = (char*)d_ws;
    size_t off = 0;
    auto alloc = [&](size_t bytes) { void* p = ws + off; off += (bytes + 255) & ~(size_t)255; return p; };

    bf16* xn   = (bf16*)alloc((size_t)Mrows * Dd * 2);
    bf16* uvwb = (bf16*)alloc((size_t)Ff * Dd * 2);
    bf16* owb  = (bf16*)alloc((size_t)Dd * Ee * 2);
    bf16* u    = (bf16*)alloc((size_t)Mrows * Ee * 2);
    bf16* qb   = (bf16*)alloc((size_t)Mrows * Ss * 2);
    bf16* kb   = (bf16*)alloc((size_t)Mrows * Ss * 2);
    bf16* agg  = (bf16*)alloc((size_t)Mrows * Ee * 2);
    bf16* vT   = (bf16*)alloc((size_t)Bb * Ee * Kk * 2);

    int n1 = Ff * Dd;
    cast_k<<<(n1 + 255) / 256, 256, 0, stream>>>(uv_w, uvwb, n1);
    int n2 = Dd * Ee;
    cast_k<<<(n2 + 255) / 256, 256, 0, stream>>>(o_w, owb, n2);

    rmsnorm_k<<<Mrows, 256, 0, stream>>>(x, g, xn);

    // GEMM1: silu(xn @ uv_w^T) -> u, vT (transposed), q, k.  grid 17*128 = 2176
    gemm_nt<0><<<2176, 256, 0, stream>>>(
        xn, Dd, uvwb, Dd, Dd / BK, 17,
        u, vT, qb, kb, gamma, beta, nullptr, nullptr, nullptr);

    // fused attention
    attn_fused<<<512, 512, 0, stream>>>(qb, kb, vT, u, agg);

    // GEMM4: out = x*res_scale + agg @ o_w^T.  grid 4*128 = 512
    gemm_nt<3><<<512, 256, 0, stream>>>(
        agg, Ee, owb, Ee, Ee / BK, 4,
        nullptr, nullptr, nullptr, nullptr, nullptr, nullptr,
        x, res_scale, out);
}

// Round 5
// 210.803 us; speedup vs baseline: 3.8010x; 1.0335x over previous
//
#include <hip/hip_runtime.h>
#include <hip/hip_bf16.h>

typedef short bf16x8 __attribute__((ext_vector_type(8)));
typedef float f32x4 __attribute__((ext_vector_type(4)));
using bf16 = __hip_bfloat16;

#define Bb 8
#define Kk 2048
#define Dd 512
#define Ee 1024
#define Ss 128
#define Mrows (Bb*Kk)
#define Ff (2*Ee+Ss)

#define BM 128
#define BN 128
#define BK 64

#define KVB 32   // kv step in fused attention

static __device__ __forceinline__ float bf2f(bf16 v){ return __bfloat162float(v); }
static __device__ __forceinline__ bf16 f2bf(float v){ return __float2bfloat16(v); }
static __device__ __forceinline__ unsigned int bfbits(float v){ bf16 b = __float2bfloat16(v); return (unsigned int)*(unsigned short*)&b; }

static __device__ __forceinline__ void gload16(const bf16* g, bf16* l) {
    __builtin_amdgcn_global_load_lds((const __attribute__((address_space(1))) void*)g,
                                     (__attribute__((address_space(3))) void*)l, 16, 0, 0);
}

union BV { int4 v; bf16 h[8]; };

// ---------------- cast f32 -> bf16 ----------------
__global__ void cast_k(const float* __restrict__ in, bf16* __restrict__ out, int n) {
    int i = blockIdx.x * blockDim.x + threadIdx.x;
    if (i < n) out[i] = f2bf(in[i]);
}

// ---------------- RMS-norm-like ----------------
__global__ __launch_bounds__(256) void rmsnorm_k(const float* __restrict__ x,
                                                 const float* __restrict__ g,
                                                 bf16* __restrict__ xn) {
    int row = blockIdx.x;
    int t = threadIdx.x;
    const float2* xr = (const float2*)(x + (size_t)row * Dd);
    float2 v = xr[t];
    float ss = v.x * v.x + v.y * v.y;
    #pragma unroll
    for (int off = 32; off; off >>= 1) ss += __shfl_down(ss, off);
    __shared__ float red[4];
    if ((t & 63) == 0) red[t >> 6] = ss;
    __syncthreads();
    float tot = red[0] + red[1] + red[2] + red[3];
    float norm = sqrtf(tot * (1.0f / Dd));
    float scale = g[0] / fmaxf(norm, 1e-5f);
    bf16* o = xn + (size_t)row * Dd;
    o[2 * t]     = f2bf(v.x * scale);
    o[2 * t + 1] = f2bf(v.y * scale);
}

// ---------------- GEMM (global_load_lds, linear LDS + XOR swizzle, dbuf) ----------------
template<int EPI>
__global__ __launch_bounds__(256, 2)
void gemm_nt(const bf16* __restrict__ A, int lda,
             const bf16* __restrict__ B, int ldb, int nk, int nTN,
             bf16* __restrict__ u, bf16* __restrict__ vT,
             bf16* __restrict__ qb, bf16* __restrict__ kb,
             const float* __restrict__ gamma, const float* __restrict__ beta,
             const float* __restrict__ x, const float* __restrict__ rsc,
             float* __restrict__ out) {
    __shared__ char smem[65536];

    const int t = threadIdx.x;
    const int bid = blockIdx.x;
    const int xcd = bid & 7;
    const int ii  = bid >> 3;
    const int tM = xcd * 16 + ii / nTN;
    const int tN = ii % nTN;
    const int rowM = tM * BM;

    const bf16* Ab = A + (size_t)rowM * lda;
    const bf16* Bp = B + (size_t)tN * BN * ldb;

    const int lane = t & 63;
    const int wave = t >> 6;
    const int wr = (wave >> 1) * 64, wc = (wave & 1) * 64;
    const int fr = lane & 15;
    const int h  = lane >> 4;
    const int q4 = h * 4;

    auto stage = [&](int buf, int k0) {
        bf16* Al = (bf16*)(smem + buf * 32768);
        bf16* Bl = Al + 8192;
        #pragma unroll
        for (int it = 0; it < 4; ++it) {
            int idx = t + it * 256;
            int r = idx >> 3, cp = idx & 7;
            int cg = (cp ^ r) & 7;
            gload16(Ab + (size_t)r * lda + k0 + cg * 8, Al + idx * 8);
            gload16(Bp + (size_t)r * ldb + k0 + cg * 8, Bl + idx * 8);
        }
    };

    f32x4 acc[4][4] = {};
    int cur = 0;
    stage(0, 0);
    for (int kt = 0; kt < nk; ++kt) {
        __syncthreads();
        if (kt + 1 < nk) stage(cur ^ 1, (kt + 1) * BK);
        const bf16* Asl = (const bf16*)(smem + cur * 32768);
        const bf16* Bsl = Asl + 8192;
        #pragma unroll
        for (int kk = 0; kk < 2; ++kk) {
            const int cs = ((4 * kk + h) ^ (fr & 7)) * 8;
            bf16x8 af[4], bv[4];
            #pragma unroll
            for (int m = 0; m < 4; ++m) af[m] = *(const bf16x8*)&Asl[(wr + m * 16 + fr) * BK + cs];
            #pragma unroll
            for (int n = 0; n < 4; ++n) bv[n] = *(const bf16x8*)&Bsl[(wc + n * 16 + fr) * BK + cs];
            #pragma unroll
            for (int m = 0; m < 4; ++m)
                #pragma unroll
                for (int n = 0; n < 4; ++n)
                    acc[m][n] = __builtin_amdgcn_mfma_f32_16x16x32_bf16(af[m], bv[n], acc[m][n], 0, 0, 0);
        }
        cur ^= 1;
    }
    __syncthreads();

    if (EPI == 0) {
        bf16 (*Ot)[140] = (bf16(*)[140])smem;
        const bool isV = (tN >= 8 && tN < 16);
        #pragma unroll
        for (int m = 0; m < 4; ++m)
            #pragma unroll
            for (int n = 0; n < 4; ++n)
                #pragma unroll
                for (int j = 0; j < 4; ++j) {
                    float val = acc[m][n][j];
                    float s = val / (1.0f + __expf(-val));
                    int rr = wr + m * 16 + q4 + j;
                    int cc = wc + n * 16 + fr;
                    if (isV) Ot[cc][rr] = f2bf(s);
                    else     Ot[rr][cc] = f2bf(s);
                }
        __syncthreads();
        if (tN < 8) {
            bf16* dst = u + (size_t)rowM * Ee + tN * 128;
            #pragma unroll
            for (int i = 0; i < 8; ++i) {
                int r = wave * 32 + (lane >> 4) + i * 4;
                int c = (lane & 15) * 8;
                *(int4*)&dst[(size_t)r * Ee + c] = *(const int4*)&Ot[r][c];
            }
        } else if (tN < 16) {
            int b  = rowM >> 11;
            int j0 = rowM & 2047;
            bf16* dst = vT + (size_t)b * Ee * Kk + (size_t)(tN - 8) * 128 * Kk + j0;
            #pragma unroll
            for (int i = 0; i < 8; ++i) {
                int e = wave * 32 + (lane >> 4) + i * 4;
                int c = (lane & 15) * 8;
                *(int4*)&dst[(size_t)e * Kk + c] = *(const int4*)&Ot[e][c];
            }
        } else {
            #pragma unroll
            for (int i = 0; i < 8; ++i) {
                int r = wave * 32 + (lane >> 4) + i * 4;
                int c = (lane & 15) * 8;
                BV sv; sv.v = *(const int4*)&Ot[r][c];
                BV qv, kv;
                #pragma unroll
                for (int e2 = 0; e2 < 8; ++e2) {
                    float s = bf2f(sv.h[e2]);
                    qv.h[e2] = f2bf(s * gamma[c + e2]       + beta[c + e2]);
                    kv.h[e2] = f2bf(s * gamma[128 + c + e2] + beta[128 + c + e2]);
                }
                *(int4*)&qb[(size_t)(rowM + r) * Ss + c] = qv.v;
                *(int4*)&kb[(size_t)(rowM + r) * Ss + c] = kv.v;
            }
        }
    } else {
        float (*Of)[134] = (float(*)[134])smem;
        const int col0 = tN * 128;
        #pragma unroll
        for (int hh = 0; hh < 2; ++hh) {
            if (hh) __syncthreads();
            if ((wave >> 1) == hh) {
                #pragma unroll
                for (int m = 0; m < 4; ++m)
                    #pragma unroll
                    for (int n = 0; n < 4; ++n)
                        #pragma unroll
                        for (int j = 0; j < 4; ++j)
                            Of[m * 16 + q4 + j][wc + n * 16 + fr] = acc[m][n][j];
            }
            __syncthreads();
            #pragma unroll
            for (int i = 0; i < 8; ++i) {
                int idx = t + i * 256;
                int r = idx >> 5, c4 = (idx & 31) * 4;
                size_t row = (size_t)(rowM + hh * 64 + r);
                float4 v  = *(const float4*)&Of[r][c4];
                float4 xv = *(const float4*)&x[row * Dd + col0 + c4];
                float4 rv = *(const float4*)&rsc[col0 + c4];
                float4 o;
                o.x = xv.x * rv.x + v.x;  o.y = xv.y * rv.y + v.y;
                o.z = xv.z * rv.z + v.z;  o.w = xv.w * rv.w + v.w;
                *(float4*)&out[row * Dd + col0 + c4] = o;
            }
        }
    }
}

// ---------------- fused attention: agg = u * (relu(QK^T/sqrt(S))^2 @ V) ----------------
// 512 threads = 8 waves, q-tile 128 x e-tile 256, KVB=32.
// LDS 57344 B -> 2 blocks/CU (the round-5 lever: cross-block MFMA/VALU overlap):
//   Kbuf[2][32*128] 16K | Vbuf[2][256*32] 32K | Pl[128*32] 8K (chunk-swizzled)
__global__ __launch_bounds__(512, 4)
void attn_fused(const bf16* __restrict__ qg, const bf16* __restrict__ kg,
                const bf16* __restrict__ vTg, const bf16* __restrict__ ug,
                bf16* __restrict__ aggg) {
    __shared__ char smem[57344];
    bf16* Kbuf = (bf16*)smem;                 // 2 x 4096 bf16
    bf16* Vbuf = (bf16*)(smem + 16384);       // 2 x 8192 bf16
    bf16* Pbuf = (bf16*)(smem + 49152);       // 4096 bf16: [128 q][32 kv], 16B-chunk swizzle

    const int blk = blockIdx.x;
    const int b  = blk & 7;
    const int t2 = blk >> 3;
    const int tE = t2 & 3;
    const int tQ = t2 >> 2;

    const bf16* Qp = qg  + ((size_t)b * Kk + (size_t)tQ * BM) * Ss;
    const bf16* Kg = kg  + (size_t)b * Kk * Ss;
    const bf16* Vg = vTg + (size_t)b * Ee * Kk + (size_t)(tE * 256) * Kk;

    const int t = threadIdx.x;
    const int lane = t & 63, wave = t >> 6;
    const int fr = lane & 15;
    const int h  = lane >> 4;
    const int q4 = h * 4;
    const int f2 = (fr >> 1) & 3;             // row-derived swizzle key (rows are 16-aligned + fr)

    // S-phase role: q-group (32 rows) x kv-half (16); PV role: q-half (64) x e-quarter (64)
    const int qgp = wave & 3, kvh = wave >> 2;
    const int wm = wave >> 2, wn = wave & 3;

    // Q fragments from global (B-operand): q = 32*qgp + 16*qs + fr
    bf16x8 qf[2][4];
    #pragma unroll
    for (int qs = 0; qs < 2; ++qs)
        #pragma unroll
        for (int ks = 0; ks < 4; ++ks)
            qf[qs][ks] = *(const bf16x8*)(Qp + (size_t)(32 * qgp + 16 * qs + fr) * Ss + 32 * ks + h * 8);

    auto stage = [&](int buf, int kvt) {
        const bf16* Kgt = Kg + (size_t)kvt * KVB * Ss;
        const bf16* Vgt = Vg + (size_t)kvt * KVB;
        bf16* Kl = Kbuf + buf * 4096;
        bf16* Vl = Vbuf + buf * 8192;
        {   // K: 32 rows x 16 chunks = 512, 1/thread
            int r = t >> 4, cp = t & 15;
            int cg = (cp & 8) | ((cp ^ (r & 7)) & 7);
            gload16(Kgt + (size_t)r * Ss + cg * 8, Kl + t * 8);
        }
        #pragma unroll
        for (int it = 0; it < 2; ++it) {   // V: 256 rows x 4 chunks = 1024, 2/thread
            int idx = t + it * 512;
            int r = idx >> 2, cp = idx & 3;
            int cg = cp ^ ((r >> 1) & 3);
            gload16(Vgt + (size_t)r * Kk + cg * 8, Vl + idx * 8);
        }
    };

    f32x4 acc[4][4] = {};
    stage(0, 0);

    for (int kv = 0; kv < Kk / KVB; ++kv) {
        const int cur = kv & 1;
        __syncthreads();   // staged cur ready (vmcnt drained); Pl free from prev PV

        // ---- S-phase (swapped): accS[qs] = K[16*kvh + fr][:] x Q[32*qgp+16*qs + fr][:]
        const bf16* Kl = Kbuf + cur * 4096;
        f32x4 accS[2] = {};
        #pragma unroll
        for (int ks = 0; ks < 4; ++ks) {
            int c = 4 * ks + h;
            int cs = (c & 8) | ((c ^ (fr & 7)) & 7);
            bf16x8 af = *(const bf16x8*)&Kl[(16 * kvh + fr) * 128 + cs * 8];
            #pragma unroll
            for (int qs = 0; qs < 2; ++qs)
                accS[qs] = __builtin_amdgcn_mfma_f32_16x16x32_bf16(af, qf[qs][ks], accS[qs], 0, 0, 0);
        }
        // relu^2 -> P. lane holds S[kv=16kvh+q4+j][q=32qgp+16qs+fr], j=0..3 -> one b64 write/qs
        #pragma unroll
        for (int qs = 0; qs < 2; ++qs) {
            int rowP = 32 * qgp + 16 * qs + fr;
            float sv[4];
            #pragma unroll
            for (int j = 0; j < 4; ++j) {
                float s = accS[qs][j] * 0.08838834764831845f;
                s = fmaxf(s, 0.0f);
                sv[j] = s * s;
            }
            uint2 w;
            w.x = bfbits(sv[0]) | (bfbits(sv[1]) << 16);
            w.y = bfbits(sv[2]) | (bfbits(sv[3]) << 16);
            int s_chunk = (2 * kvh + (h >> 1)) ^ f2;
            *(uint2*)&Pbuf[rowP * 32 + s_chunk * 8 + 4 * (h & 1)] = w;
        }
        __syncthreads();   // P visible

        if (kv + 1 < Kk / KVB) stage(cur ^ 1, kv + 1);   // async, drains at next top barrier

        // ---- PV: acc += P[wm*64..][32] @ V[32][wn*64..]
        const bf16* Vl = Vbuf + cur * 8192;
        __builtin_amdgcn_s_setprio(1);
        {
            bf16x8 af[4], bv[4];
            #pragma unroll
            for (int m = 0; m < 4; ++m) {
                int row = wm * 64 + m * 16 + fr;
                af[m] = *(const bf16x8*)&Pbuf[row * 32 + (h ^ f2) * 8];
            }
            #pragma unroll
            for (int n = 0; n < 4; ++n) {
                int row = wn * 64 + n * 16 + fr;
                bv[n] = *(const bf16x8*)&Vl[row * 32 + (h ^ f2) * 8];
            }
            #pragma unroll
            for (int m = 0; m < 4; ++m)
                #pragma unroll
                for (int n = 0; n < 4; ++n)
                    acc[m][n] = __builtin_amdgcn_mfma_f32_16x16x32_bf16(af[m], bv[n], acc[m][n], 0, 0, 0);
        }
        __builtin_amdgcn_s_setprio(0);
    }

    // ---- epilogue in two 128-col passes: agg = acc * u
    bf16 (*Ot)[136] = (bf16(*)[136])smem;   // 128x136x2 = 34816 <= 57344
    const size_t rowbase = (size_t)b * Kk + (size_t)tQ * BM;
    #pragma unroll
    for (int half = 0; half < 2; ++half) {
        __syncthreads();
        if ((wn >> 1) == half) {
            #pragma unroll
            for (int m = 0; m < 4; ++m)
                #pragma unroll
                for (int n = 0; n < 4; ++n)
                    #pragma unroll
                    for (int j = 0; j < 4; ++j)
                        Ot[wm * 64 + m * 16 + q4 + j][(wn & 1) * 64 + n * 16 + fr] = f2bf(acc[m][n][j]);
        }
        __syncthreads();
        const bf16* usrc = ug   + rowbase * Ee + tE * 256 + half * 128;
        bf16*       adst = aggg + rowbase * Ee + tE * 256 + half * 128;
        #pragma unroll
        for (int i = 0; i < 4; ++i) {
            int idx = t + i * 512;
            int r = idx >> 4, c = (idx & 15) * 8;
            BV ov, uv2, rv;
            ov.v  = *(const int4*)&Ot[r][c];
            uv2.v = *(const int4*)&usrc[(size_t)r * Ee + c];
            #pragma unroll
            for (int e2 = 0; e2 < 8; ++e2) rv.h[e2] = f2bf(bf2f(ov.h[e2]) * bf2f(uv2.h[e2]));
            *(int4*)&adst[(size_t)r * Ee + c] = rv.v;
        }
    }
}

extern "C" void kernel_launch(void* const* d_in, const int* in_sizes, int n_in,
                              void* d_out, int out_size, void* d_ws, size_t ws_size,
                              hipStream_t stream) {
    const float* x         = (const float*)d_in[0];
    const float* uv_w      = (const float*)d_in[1];
    const float* o_w       = (const float*)d_in[2];
    const float* gamma     = (const float*)d_in[3];
    const float* beta      = (const float*)d_in[4];
    const float* g         = (const float*)d_in[5];
    const float* res_scale = (const float*)d_in[6];
    float* out = (float*)d_out;

    char* ws = (char*)d_ws;
    size_t off = 0;
    auto alloc = [&](size_t bytes) { void* p = ws + off; off += (bytes + 255) & ~(size_t)255; return p; };

    bf16* xn   = (bf16*)alloc((size_t)Mrows * Dd * 2);
    bf16* uvwb = (bf16*)alloc((size_t)Ff * Dd * 2);
    bf16* owb  = (bf16*)alloc((size_t)Dd * Ee * 2);
    bf16* u    = (bf16*)alloc((size_t)Mrows * Ee * 2);
    bf16* qb   = (bf16*)alloc((size_t)Mrows * Ss * 2);
    bf16* kb   = (bf16*)alloc((size_t)Mrows * Ss * 2);
    bf16* agg  = (bf16*)alloc((size_t)Mrows * Ee * 2);
    bf16* vT   = (bf16*)alloc((size_t)Bb * Ee * Kk * 2);

    int n1 = Ff * Dd;
    cast_k<<<(n1 + 255) / 256, 256, 0, stream>>>(uv_w, uvwb, n1);
    int n2 = Dd * Ee;
    cast_k<<<(n2 + 255) / 256, 256, 0, stream>>>(o_w, owb, n2);

    rmsnorm_k<<<Mrows, 256, 0, stream>>>(x, g, xn);

    // GEMM1: silu(xn @ uv_w^T) -> u, vT (transposed), q, k.  grid 17*128 = 2176
    gemm_nt<0><<<2176, 256, 0, stream>>>(
        xn, Dd, uvwb, Dd, Dd / BK, 17,
        u, vT, qb, kb, gamma, beta, nullptr, nullptr, nullptr);

    // fused attention
    attn_fused<<<512, 512, 0, stream>>>(qb, kb, vT, u, agg);

    // GEMM4: out = x*res_scale + agg @ o_w^T.  grid 4*128 = 512
    gemm_nt<3><<<512, 256, 0, stream>>>(
        agg, Ee, owb, Ee, Ee / BK, 4,
        nullptr, nullptr, nullptr, nullptr, nullptr, nullptr,
        x, res_scale, out);
}